// Round 1
// baseline (264.154 us; speedup 1.0000x reference)
//
#include <hip/hip_runtime.h>

#define HH 192
#define WW 192
#define BATCH 16
#define TX 32
#define TY 8
#define HALO 2
#define TW (TX + 2*HALO)   /* 36 */
#define TH (TY + 2*HALO)   /* 12 */
#define PLANE (HH*WW)              /* 36864 */
#define NELEM (BATCH*2*PLANE)      /* 1179648 */

// Scale + flip the 6 FD kernels into the 8 conv kernels used per RHS eval.
// K8 layout: [8][5][5] row-major.  j<6: kernels[j]*DX^-ord[j];
// j==6: -K[1] flipped in x; j==7: -K[2] flipped in y.
__global__ void prep_kernel(const float* __restrict__ kern, float* __restrict__ K8) {
    int t = blockIdx.x * blockDim.x + threadIdx.x;
    if (t >= 200) return;
    const float inv  = 1.0f / 0.0327249f;
    const float inv2 = inv * inv;
    const float sc[6] = {1.0f, inv, inv, inv2, inv2, inv2};
    int j = t / 25, r = t % 25, dy = r / 5, dx = r % 5;
    float v;
    if (j < 6)       v =  kern[j*25 + dy*5 + dx] * sc[j];
    else if (j == 6) v = -kern[1*25 + dy*5 + (4-dx)] * sc[1];
    else             v = -kern[2*25 + (4-dy)*5 + dx] * sc[2];
    K8[t] = v;
}

// One RHS eval fused with axpy: uout = ubase + alpha * rhs(uin).
// Weights read via uniform (scalar) global loads -> SGPR operands; field tile
// staged in LDS with periodic halo.
__global__ __launch_bounds__(256) void rhs_kernel(
    const float* __restrict__ uin,
    const float* __restrict__ ubase,
    float* __restrict__ uout,
    const float* __restrict__ K8,
    const float* __restrict__ pw0, const float* __restrict__ pb0,
    const float* __restrict__ pw1, const float* __restrict__ pb1,
    const float* __restrict__ pwf, const float* __restrict__ pbf,
    float alpha)
{
    __shared__ float sh[2][TH][TW];
    const int b   = blockIdx.z;
    const int ty0 = blockIdx.y * TY;
    const int tx0 = blockIdx.x * TX;
    const int tid = threadIdx.y * TX + threadIdx.x;

    const float* uin_b = uin + (size_t)b * 2 * PLANE;

    // Stage tile + periodic halo for both channels.
    for (int i = tid; i < TH*TW; i += TX*TY) {
        int ly = i / TW, lx = i % TW;
        int gy = ty0 + ly - HALO; if (gy < 0) gy += HH; if (gy >= HH) gy -= HH;
        int gx = tx0 + lx - HALO; if (gx < 0) gx += WW; if (gx >= WW) gx -= WW;
        int gidx = gy * WW + gx;
        sh[0][ly][lx] = uin_b[gidx];
        sh[1][ly][lx] = uin_b[PLANE + gidx];
    }
    __syncthreads();

    const int tx = threadIdx.x, ty = threadIdx.y;

    // 5x5 windows for both channels into registers (50 VGPRs).
    float win[2][5][5];
    #pragma unroll
    for (int c = 0; c < 2; ++c)
        #pragma unroll
        for (int dy = 0; dy < 5; ++dy)
            #pragma unroll
            for (int dx = 0; dx < 5; ++dx)
                win[c][dy][dx] = sh[c][ty+dy][tx+dx];

    // 16 dot products (cross-correlation, no flip — matches XLA conv).
    float D[2][8];
    #pragma unroll
    for (int c = 0; c < 2; ++c) {
        #pragma unroll
        for (int j = 0; j < 8; ++j) {
            float acc = 0.0f;
            #pragma unroll
            for (int o = 0; o < 25; ++o)
                acc += win[c][o/5][o%5] * K8[j*25 + o];
            D[c][j] = acc;
        }
    }

    // base features z[c*6+j] = D[c][j]
    float z[12];
    #pragma unroll
    for (int c = 0; c < 2; ++c)
        #pragma unroll
        for (int j = 0; j < 6; ++j)
            z[c*6+j] = D[c][j];

    float xs[12];
    #pragma unroll
    for (int i = 0; i < 12; ++i) xs[i] = z[i];

    // Upwind selection: analytic gradient of poly_k at z, channels k*6+1, k*6+2.
    #pragma unroll
    for (int k = 0; k < 2; ++k) {
        const float* W0 = pw0 + k*24;   // [2][12]
        const float* B0 = pb0 + k*2;    // [2]
        const float* W1 = pw1 + k*26;   // [2][13]
        const float* B1 = pb1 + k*2;    // [2]
        const float* WF = pwf + k*14;   // [14]

        float o0 = B0[0], o1 = B0[1];
        #pragma unroll
        for (int i = 0; i < 12; ++i) { o0 += W0[i]*z[i]; o1 += W0[12+i]*z[i]; }
        float p1 = o0*o1;
        float q0 = B1[0] + W1[12]*p1;
        float q1 = B1[1] + W1[25]*p1;
        #pragma unroll
        for (int i = 0; i < 12; ++i) { q0 += W1[i]*z[i]; q1 += W1[13+i]*z[i]; }

        const int i1 = k*6+1, i2 = k*6+2;
        {
            float t = o1*W0[i1] + o0*W0[12+i1];
            float g = WF[i1] + WF[12]*t
                    + WF[13]*(q1*(W1[i1] + W1[12]*t) + q0*(W1[13+i1] + W1[25]*t));
            xs[i1] = (g > 0.0f) ? z[i1] : D[k][6];
        }
        {
            float t = o1*W0[i2] + o0*W0[12+i2];
            float g = WF[i2] + WF[12]*t
                    + WF[13]*(q1*(W1[i2] + W1[12]*t) + q0*(W1[13+i2] + W1[25]*t));
            xs[i2] = (g > 0.0f) ? z[i2] : D[k][7];
        }
    }

    // Poly forward at selected features (note: poly_0 sees k=1's selections too).
    float uadd[2];
    #pragma unroll
    for (int k = 0; k < 2; ++k) {
        const float* W0 = pw0 + k*24;
        const float* B0 = pb0 + k*2;
        const float* W1 = pw1 + k*26;
        const float* B1 = pb1 + k*2;
        const float* WF = pwf + k*14;
        const float* BF = pbf + k;

        float o0 = B0[0], o1 = B0[1];
        #pragma unroll
        for (int i = 0; i < 12; ++i) { o0 += W0[i]*xs[i]; o1 += W0[12+i]*xs[i]; }
        float p1 = o0*o1;
        float q0 = B1[0] + W1[12]*p1;
        float q1 = B1[1] + W1[25]*p1;
        #pragma unroll
        for (int i = 0; i < 12; ++i) { q0 += W1[i]*xs[i]; q1 += W1[13+i]*xs[i]; }
        float p2 = q0*q1;
        float y = BF[0] + WF[12]*p1 + WF[13]*p2;
        #pragma unroll
        for (int i = 0; i < 12; ++i) y += WF[i]*xs[i];
        uadd[k] = y;
    }

    const size_t oidx = (size_t)b * 2 * PLANE + (size_t)(ty0+ty) * WW + (tx0+tx);
    uout[oidx]         = ubase[oidx]         + alpha * uadd[0];
    uout[oidx + PLANE] = ubase[oidx + PLANE] + alpha * uadd[1];
}

extern "C" void kernel_launch(void* const* d_in, const int* in_sizes, int n_in,
                              void* d_out, int out_size, void* d_ws, size_t ws_size,
                              hipStream_t stream)
{
    const float* init = (const float*)d_in[0];
    const float* kern = (const float*)d_in[1];
    const float* pw0  = (const float*)d_in[2];
    const float* pb0  = (const float*)d_in[3];
    const float* pw1  = (const float*)d_in[4];
    const float* pb1  = (const float*)d_in[5];
    const float* pwf  = (const float*)d_in[6];
    const float* pbf  = (const float*)d_in[7];
    float* out = (float*)d_out;

    float* K8   = (float*)d_ws;        // 200 floats (padded to 256)
    float* bufA = K8 + 256;            // NELEM floats: u_n
    float* bufH = bufA + NELEM;        // NELEM floats: u_half

    prep_kernel<<<dim3(1), dim3(256), 0, stream>>>(kern, K8);

    const dim3 grid(WW/TX, HH/TY, BATCH);
    const dim3 block(TX, TY);
    const float DTF = 0.2f, DTH = 0.1f;

    // T=1 -> 5 RK2 (midpoint) steps, 2 RHS evals each (sequential dependency).
    // step 1 (reads init; never write d_in)
    rhs_kernel<<<grid, block, 0, stream>>>(init, init, bufH, K8, pw0,pb0,pw1,pb1,pwf,pbf, DTH);
    rhs_kernel<<<grid, block, 0, stream>>>(bufH, init, bufA, K8, pw0,pb0,pw1,pb1,pwf,pbf, DTF);
    // steps 2..4
    for (int s = 0; s < 3; ++s) {
        rhs_kernel<<<grid, block, 0, stream>>>(bufA, bufA, bufH, K8, pw0,pb0,pw1,pb1,pwf,pbf, DTH);
        rhs_kernel<<<grid, block, 0, stream>>>(bufH, bufA, bufA, K8, pw0,pb0,pw1,pb1,pwf,pbf, DTF);
    }
    // step 5 — final RHS writes d_out directly
    rhs_kernel<<<grid, block, 0, stream>>>(bufA, bufA, bufH, K8, pw0,pb0,pw1,pb1,pwf,pbf, DTH);
    rhs_kernel<<<grid, block, 0, stream>>>(bufH, bufA, out,  K8, pw0,pb0,pw1,pb1,pwf,pbf, DTF);
}

// Round 2
// 244.174 us; speedup vs baseline: 1.0818x; 1.0818x over previous
//
#include <hip/hip_runtime.h>

#define HH 192
#define WW 192
#define BATCH 16
#define PLANE (HH*WW)              /* 36864 */
#define NELEM (BATCH*2*PLANE)      /* 1179648 */

// Tile: 64 px wide (32 threads x 2 px) x 8 rows. Halo 2 each side.
#define BX 32
#define BY 8
#define TILEX 64
#define TILEY 8
#define SW 68   /* TILEX + 4 */
#define SH2 12  /* TILEY + 4 */

// K8T layout: tap-major [25][8] so the 8 per-tap weights are contiguous
// (one s_load_dwordx8). j<6: kernels[j]*DX^-ord; j==6: -K[1] x-flip;
// j==7: -K[2] y-flip.
__global__ void prep_kernel(const float* __restrict__ kern, float* __restrict__ K8T) {
    int t = blockIdx.x * blockDim.x + threadIdx.x;
    if (t >= 200) return;
    const float inv  = 1.0f / 0.0327249f;
    const float inv2 = inv * inv;
    const float sc[6] = {1.0f, inv, inv, inv2, inv2, inv2};
    int o = t / 8, j = t % 8, dy = o / 5, dx = o % 5;
    float v;
    if (j < 6)       v =  kern[j*25 + dy*5 + dx] * sc[j];
    else if (j == 6) v = -kern[1*25 + dy*5 + (4-dx)] * sc[1];
    else             v = -kern[2*25 + (4-dy)*5 + dx] * sc[2];
    K8T[o*8 + j] = v;
}

// SymNet poly: gradient-based upwind selection + forward, one spatial point.
// z[12] = base features, f01[c]/f10[c] = flipped 1st-order stencils.
__device__ __forceinline__ void poly_point(
    const float* __restrict__ pw0, const float* __restrict__ pb0,
    const float* __restrict__ pw1, const float* __restrict__ pb1,
    const float* __restrict__ pwf, const float* __restrict__ pbf,
    const float z[12], const float f01[2], const float f10[2], float uadd[2])
{
    float xs[12];
    #pragma unroll
    for (int i = 0; i < 12; ++i) xs[i] = z[i];

    // Upwind selection via analytic d(poly_k)/dz at z.
    #pragma unroll
    for (int k = 0; k < 2; ++k) {
        const float* W0 = pw0 + k*24;   // [2][12]
        const float* B0 = pb0 + k*2;
        const float* W1 = pw1 + k*26;   // [2][13]
        const float* B1 = pb1 + k*2;
        const float* WF = pwf + k*14;   // [14]

        float o0 = B0[0], o1 = B0[1];
        #pragma unroll
        for (int i = 0; i < 12; ++i) { o0 += W0[i]*z[i]; o1 += W0[12+i]*z[i]; }
        float p1 = o0*o1;
        float q0 = B1[0] + W1[12]*p1;
        float q1 = B1[1] + W1[25]*p1;
        #pragma unroll
        for (int i = 0; i < 12; ++i) { q0 += W1[i]*z[i]; q1 += W1[13+i]*z[i]; }

        const int i1 = k*6+1, i2 = k*6+2;
        {
            float t = o1*W0[i1] + o0*W0[12+i1];
            float g = WF[i1] + WF[12]*t
                    + WF[13]*(q1*(W1[i1] + W1[12]*t) + q0*(W1[13+i1] + W1[25]*t));
            xs[i1] = (g > 0.0f) ? z[i1] : f01[k];
        }
        {
            float t = o1*W0[i2] + o0*W0[12+i2];
            float g = WF[i2] + WF[12]*t
                    + WF[13]*(q1*(W1[i2] + W1[12]*t) + q0*(W1[13+i2] + W1[25]*t));
            xs[i2] = (g > 0.0f) ? z[i2] : f10[k];
        }
    }

    // Forward poly at selected features.
    #pragma unroll
    for (int k = 0; k < 2; ++k) {
        const float* W0 = pw0 + k*24;
        const float* B0 = pb0 + k*2;
        const float* W1 = pw1 + k*26;
        const float* B1 = pb1 + k*2;
        const float* WF = pwf + k*14;
        const float* BF = pbf + k;

        float o0 = B0[0], o1 = B0[1];
        #pragma unroll
        for (int i = 0; i < 12; ++i) { o0 += W0[i]*xs[i]; o1 += W0[12+i]*xs[i]; }
        float p1 = o0*o1;
        float q0 = B1[0] + W1[12]*p1;
        float q1 = B1[1] + W1[25]*p1;
        #pragma unroll
        for (int i = 0; i < 12; ++i) { q0 += W1[i]*xs[i]; q1 += W1[13+i]*xs[i]; }
        float p2 = q0*q1;
        float y = BF[0] + WF[12]*p1 + WF[13]*p2;
        #pragma unroll
        for (int i = 0; i < 12; ++i) y += WF[i]*xs[i];
        uadd[k] = y;
    }
}

// One RHS eval fused with axpy: uout = ubase + alpha * rhs(uin).
// 2 px per thread along x; channels processed sequentially to cap VGPRs.
__global__ __launch_bounds__(256, 4) void rhs_kernel(
    const float* __restrict__ uin,
    const float* __restrict__ ubase,
    float* __restrict__ uout,
    const float* __restrict__ K8T,
    const float* __restrict__ pw0, const float* __restrict__ pb0,
    const float* __restrict__ pw1, const float* __restrict__ pb1,
    const float* __restrict__ pwf, const float* __restrict__ pbf,
    float alpha)
{
    __shared__ float sh[2][SH2][SW];
    const int b   = blockIdx.z;
    const int ty0 = blockIdx.y * TILEY;
    const int tx0 = blockIdx.x * TILEX;
    const int tx  = threadIdx.x, ty = threadIdx.y;
    const int tid = ty * BX + tx;

    const float* uin_b = uin + (size_t)b * 2 * PLANE;

    // Stage tile + periodic halo, both channels (2*12*68 = 1632 elements).
    for (int i = tid; i < 2*SH2*SW; i += BX*BY) {
        int c = i / (SH2*SW), r = i % (SH2*SW), ly = r / SW, lx = r % SW;
        int gy = ty0 + ly - 2; if (gy < 0) gy += HH; if (gy >= HH) gy -= HH;
        int gx = tx0 + lx - 2; if (gx < 0) gx += WW; if (gx >= WW) gx -= WW;
        sh[c][ly][lx] = uin_b[c*PLANE + gy*WW + gx];
    }
    __syncthreads();

    // D[px][ch][j]: 16 dot products per pixel (cross-correlation, no flip).
    float D[2][2][8];
    #pragma unroll
    for (int p = 0; p < 2; ++p)
        #pragma unroll
        for (int c = 0; c < 2; ++c)
            #pragma unroll
            for (int j = 0; j < 8; ++j)
                D[p][c][j] = 0.0f;

    const int x2 = 2 * tx;
    #pragma unroll
    for (int c = 0; c < 2; ++c) {
        float win[5][6];
        #pragma unroll
        for (int dy = 0; dy < 5; ++dy)
            #pragma unroll
            for (int dx = 0; dx < 6; ++dx)
                win[dy][dx] = sh[c][ty+dy][x2+dx];
        #pragma unroll
        for (int o = 0; o < 25; ++o) {
            const int dy = o / 5, dx = o % 5;
            #pragma unroll
            for (int j = 0; j < 8; ++j) {
                const float w = K8T[o*8 + j];
                D[0][c][j] += win[dy][dx]   * w;
                D[1][c][j] += win[dy][dx+1] * w;
            }
        }
    }

    float res[2][2];   // [px][ch]
    #pragma unroll
    for (int p = 0; p < 2; ++p) {
        float z[12], f01[2], f10[2];
        #pragma unroll
        for (int c = 0; c < 2; ++c) {
            #pragma unroll
            for (int j = 0; j < 6; ++j) z[c*6+j] = D[p][c][j];
            f01[c] = D[p][c][6];
            f10[c] = D[p][c][7];
        }
        poly_point(pw0, pb0, pw1, pb1, pwf, pbf, z, f01, f10, res[p]);
    }

    const int oy = ty0 + ty, ox = tx0 + x2;
    const size_t o0 = (size_t)b * 2 * PLANE + (size_t)oy * WW + ox;
    const float2 base0 = *(const float2*)(ubase + o0);
    const float2 base1 = *(const float2*)(ubase + o0 + PLANE);
    float2 r0, r1;
    r0.x = base0.x + alpha * res[0][0];
    r0.y = base0.y + alpha * res[1][0];
    r1.x = base1.x + alpha * res[0][1];
    r1.y = base1.y + alpha * res[1][1];
    *(float2*)(uout + o0)         = r0;
    *(float2*)(uout + o0 + PLANE) = r1;
}

extern "C" void kernel_launch(void* const* d_in, const int* in_sizes, int n_in,
                              void* d_out, int out_size, void* d_ws, size_t ws_size,
                              hipStream_t stream)
{
    const float* init = (const float*)d_in[0];
    const float* kern = (const float*)d_in[1];
    const float* pw0  = (const float*)d_in[2];
    const float* pb0  = (const float*)d_in[3];
    const float* pw1  = (const float*)d_in[4];
    const float* pb1  = (const float*)d_in[5];
    const float* pwf  = (const float*)d_in[6];
    const float* pbf  = (const float*)d_in[7];
    float* out = (float*)d_out;

    float* K8T  = (float*)d_ws;        // 200 floats (padded to 256)
    float* bufA = K8T + 256;           // NELEM floats: u_n
    float* bufH = bufA + NELEM;        // NELEM floats: u_half

    prep_kernel<<<dim3(1), dim3(256), 0, stream>>>(kern, K8T);

    const dim3 grid(WW/TILEX, HH/TILEY, BATCH);   // (3, 24, 16)
    const dim3 block(BX, BY);                     // (32, 8)
    const float DTF = 0.2f, DTH = 0.1f;

    // T=1 -> 5 RK2 (midpoint) steps, 2 RHS evals each (sequential dependency).
    rhs_kernel<<<grid, block, 0, stream>>>(init, init, bufH, K8T, pw0,pb0,pw1,pb1,pwf,pbf, DTH);
    rhs_kernel<<<grid, block, 0, stream>>>(bufH, init, bufA, K8T, pw0,pb0,pw1,pb1,pwf,pbf, DTF);
    for (int s = 0; s < 3; ++s) {
        rhs_kernel<<<grid, block, 0, stream>>>(bufA, bufA, bufH, K8T, pw0,pb0,pw1,pb1,pwf,pbf, DTH);
        rhs_kernel<<<grid, block, 0, stream>>>(bufH, bufA, bufA, K8T, pw0,pb0,pw1,pb1,pwf,pbf, DTF);
    }
    rhs_kernel<<<grid, block, 0, stream>>>(bufA, bufA, bufH, K8T, pw0,pb0,pw1,pb1,pwf,pbf, DTH);
    rhs_kernel<<<grid, block, 0, stream>>>(bufH, bufA, out,  K8T, pw0,pb0,pw1,pb1,pwf,pbf, DTF);
}

// Round 3
// 241.409 us; speedup vs baseline: 1.0942x; 1.0115x over previous
//
#include <hip/hip_runtime.h>

#define HH 192
#define WW 192
#define BATCH 16
#define PLANE (HH*WW)              /* 36864 */
#define NELEM (BATCH*2*PLANE)      /* 1179648 */

// Tile: 64 px wide x 8 rows, 256 threads, 2 px per thread. Halo 2 each side.
#define TILEX 64
#define TILEY 8
#define SW 68   /* TILEX + 4 */
#define SH2 12  /* TILEY + 4 */

// K8T layout: tap-major [25][8] so the 8 per-tap weights are contiguous
// (one s_load_dwordx8). j<6: kernels[j]*DX^-ord; j==6: -K[1] x-flip;
// j==7: -K[2] y-flip.
__global__ void prep_kernel(const float* __restrict__ kern, float* __restrict__ K8T) {
    int t = blockIdx.x * blockDim.x + threadIdx.x;
    if (t >= 200) return;
    const float inv  = 1.0f / 0.0327249f;
    const float inv2 = inv * inv;
    const float sc[6] = {1.0f, inv, inv, inv2, inv2, inv2};
    int o = t / 8, j = t % 8, dy = o / 5, dx = o % 5;
    float v;
    if (j < 6)       v =  kern[j*25 + dy*5 + dx] * sc[j];
    else if (j == 6) v = -kern[1*25 + dy*5 + (4-dx)] * sc[1];
    else             v = -kern[2*25 + (4-dy)*5 + dx] * sc[2];
    K8T[o*8 + j] = v;
}

// One RHS eval fused with axpy: uout = ubase + alpha * rhs(uin).
// 2 px/thread; channels sequential in conv; poly runs both px in lockstep so
// every weight s_load feeds 2 fmas and dep chains interleave (2x ILP).
__global__ __launch_bounds__(256, 4) void rhs_kernel(
    const float* __restrict__ uin,
    const float* __restrict__ ubase,
    float* __restrict__ uout,
    const float* __restrict__ K8T,
    const float* __restrict__ pw0, const float* __restrict__ pb0,
    const float* __restrict__ pw1, const float* __restrict__ pb1,
    const float* __restrict__ pwf, const float* __restrict__ pbf,
    float alpha)
{
    __shared__ float sh[2][SH2][SW];
    const int b   = blockIdx.z;
    const int ty0 = blockIdx.y * TILEY;
    const int tx0 = blockIdx.x * TILEX;
    const int tid = threadIdx.x;

    const float* uin_b = uin + (size_t)b * 2 * PLANE;

    // ---- Staging: div/mod-free. 64x4 layout covers cols 0..63 of all 12
    // rows (3 strided rows/thread); first 96 threads cover cols 64..67.
    {
        const int row = tid >> 6;       // 0..3
        const int col = tid & 63;       // 0..63
        int gx = tx0 + col - 2;
        if (gx < 0) gx += WW;           // tx0+col-2 <= 128+61 < 192, no high wrap
        #pragma unroll
        for (int r = 0; r < 3; ++r) {
            const int ly = row + 4*r;
            int gy = ty0 + ly - 2; if (gy < 0) gy += HH; if (gy >= HH) gy -= HH;
            const int gi = gy*WW + gx;
            sh[0][ly][col] = uin_b[gi];
            sh[1][ly][col] = uin_b[PLANE + gi];
        }
        if (tid < 96) {
            const int ch = tid & 1, lxo = (tid >> 1) & 3, ly = tid >> 3;
            int gx2 = tx0 + 64 + lxo - 2;         // 62..65 + tx0
            if (gx2 >= WW) gx2 -= WW;             // no negative case
            int gy = ty0 + ly - 2; if (gy < 0) gy += HH; if (gy >= HH) gy -= HH;
            sh[ch][ly][64 + lxo] = uin_b[ch*PLANE + gy*WW + gx2];
        }
    }
    __syncthreads();

    const int cy = tid >> 5;            // 0..7
    const int x2 = (tid & 31) * 2;      // 0,2,..,62

    // ---- Conv: D[px][ch][j], 16 dot products per pixel.
    float D[2][2][8];
    #pragma unroll
    for (int p = 0; p < 2; ++p)
        #pragma unroll
        for (int c = 0; c < 2; ++c)
            #pragma unroll
            for (int j = 0; j < 8; ++j)
                D[p][c][j] = 0.0f;

    #pragma unroll
    for (int c = 0; c < 2; ++c) {
        float win[5][6];
        #pragma unroll
        for (int dy = 0; dy < 5; ++dy)
            #pragma unroll
            for (int dx = 0; dx < 6; ++dx)
                win[dy][dx] = sh[c][cy+dy][x2+dx];
        #pragma unroll
        for (int o = 0; o < 25; ++o) {
            const int dy = o / 5, dx = o % 5;
            #pragma unroll
            for (int j = 0; j < 8; ++j) {
                const float w = K8T[o*8 + j];
                D[0][c][j] += win[dy][dx]   * w;
                D[1][c][j] += win[dy][dx+1] * w;
            }
        }
    }

    // Base features: Z(p,i) aliases D[p][i/6][i%6] (i compile-time const).
#define ZF(p,i) D[p][(i)/6][(i)%6]

    float xs[2][12];
    #pragma unroll
    for (int p = 0; p < 2; ++p)
        #pragma unroll
        for (int i = 0; i < 12; ++i)
            xs[p][i] = ZF(p, i);

    // ---- Upwind: analytic d(poly_k)/dz at base z, both px in lockstep.
    #pragma unroll
    for (int k = 0; k < 2; ++k) {
        const float* W0 = pw0 + k*24;   // [2][12]
        const float* B0 = pb0 + k*2;
        const float* W1 = pw1 + k*26;   // [2][13]
        const float* B1 = pb1 + k*2;
        const float* WF = pwf + k*14;   // [14]

        float o0[2], o1[2], q0[2], q1[2];
        #pragma unroll
        for (int p = 0; p < 2; ++p) { o0[p] = B0[0]; o1[p] = B0[1]; }
        #pragma unroll
        for (int i = 0; i < 12; ++i) {
            const float wa = W0[i], wb = W0[12+i];
            #pragma unroll
            for (int p = 0; p < 2; ++p) {
                o0[p] += wa * ZF(p, i);
                o1[p] += wb * ZF(p, i);
            }
        }
        #pragma unroll
        for (int p = 0; p < 2; ++p) {
            const float pp = o0[p]*o1[p];
            q0[p] = B1[0] + W1[12]*pp;
            q1[p] = B1[1] + W1[25]*pp;
        }
        #pragma unroll
        for (int i = 0; i < 12; ++i) {
            const float wa = W1[i], wb = W1[13+i];
            #pragma unroll
            for (int p = 0; p < 2; ++p) {
                q0[p] += wa * ZF(p, i);
                q1[p] += wb * ZF(p, i);
            }
        }

        const int i1 = k*6+1, i2 = k*6+2;
        #pragma unroll
        for (int p = 0; p < 2; ++p) {
            {
                const float t = o1[p]*W0[i1] + o0[p]*W0[12+i1];
                const float g = WF[i1] + WF[12]*t
                    + WF[13]*(q1[p]*(W1[i1] + W1[12]*t) + q0[p]*(W1[13+i1] + W1[25]*t));
                xs[p][i1] = (g > 0.0f) ? ZF(p, i1) : D[p][k][6];
            }
            {
                const float t = o1[p]*W0[i2] + o0[p]*W0[12+i2];
                const float g = WF[i2] + WF[12]*t
                    + WF[13]*(q1[p]*(W1[i2] + W1[12]*t) + q0[p]*(W1[13+i2] + W1[25]*t));
                xs[p][i2] = (g > 0.0f) ? ZF(p, i2) : D[p][k][7];
            }
        }
    }

    // ---- Forward poly at selected features, both px in lockstep.
    float res[2][2];   // [px][k]
    #pragma unroll
    for (int k = 0; k < 2; ++k) {
        const float* W0 = pw0 + k*24;
        const float* B0 = pb0 + k*2;
        const float* W1 = pw1 + k*26;
        const float* B1 = pb1 + k*2;
        const float* WF = pwf + k*14;
        const float* BF = pbf + k;

        float o0[2], o1[2], q0[2], q1[2], y[2];
        #pragma unroll
        for (int p = 0; p < 2; ++p) { o0[p] = B0[0]; o1[p] = B0[1]; }
        #pragma unroll
        for (int i = 0; i < 12; ++i) {
            const float wa = W0[i], wb = W0[12+i];
            #pragma unroll
            for (int p = 0; p < 2; ++p) {
                o0[p] += wa * xs[p][i];
                o1[p] += wb * xs[p][i];
            }
        }
        #pragma unroll
        for (int p = 0; p < 2; ++p) {
            const float pp = o0[p]*o1[p];
            q0[p] = B1[0] + W1[12]*pp;
            q1[p] = B1[1] + W1[25]*pp;
            y[p]  = BF[0] + WF[12]*pp;
        }
        #pragma unroll
        for (int i = 0; i < 12; ++i) {
            const float wa = W1[i], wb = W1[13+i], wc = WF[i];
            #pragma unroll
            for (int p = 0; p < 2; ++p) {
                q0[p] += wa * xs[p][i];
                q1[p] += wb * xs[p][i];
                y[p]  += wc * xs[p][i];
            }
        }
        #pragma unroll
        for (int p = 0; p < 2; ++p)
            res[p][k] = y[p] + WF[13]*(q0[p]*q1[p]);
    }

    const int oy = ty0 + cy, ox = tx0 + x2;
    const size_t o0i = (size_t)b * 2 * PLANE + (size_t)oy * WW + ox;
    const float2 base0 = *(const float2*)(ubase + o0i);
    const float2 base1 = *(const float2*)(ubase + o0i + PLANE);
    float2 r0, r1;
    r0.x = base0.x + alpha * res[0][0];
    r0.y = base0.y + alpha * res[1][0];
    r1.x = base1.x + alpha * res[0][1];
    r1.y = base1.y + alpha * res[1][1];
    *(float2*)(uout + o0i)         = r0;
    *(float2*)(uout + o0i + PLANE) = r1;
}

extern "C" void kernel_launch(void* const* d_in, const int* in_sizes, int n_in,
                              void* d_out, int out_size, void* d_ws, size_t ws_size,
                              hipStream_t stream)
{
    const float* init = (const float*)d_in[0];
    const float* kern = (const float*)d_in[1];
    const float* pw0  = (const float*)d_in[2];
    const float* pb0  = (const float*)d_in[3];
    const float* pw1  = (const float*)d_in[4];
    const float* pb1  = (const float*)d_in[5];
    const float* pwf  = (const float*)d_in[6];
    const float* pbf  = (const float*)d_in[7];
    float* out = (float*)d_out;

    float* K8T  = (float*)d_ws;        // 200 floats (padded to 256)
    float* bufA = K8T + 256;           // NELEM floats: u_n
    float* bufH = bufA + NELEM;        // NELEM floats: u_half

    prep_kernel<<<dim3(1), dim3(256), 0, stream>>>(kern, K8T);

    const dim3 grid(WW/TILEX, HH/TILEY, BATCH);   // (3, 24, 16)
    const dim3 block(256);
    const float DTF = 0.2f, DTH = 0.1f;

    // T=1 -> 5 RK2 (midpoint) steps, 2 RHS evals each (sequential dependency).
    rhs_kernel<<<grid, block, 0, stream>>>(init, init, bufH, K8T, pw0,pb0,pw1,pb1,pwf,pbf, DTH);
    rhs_kernel<<<grid, block, 0, stream>>>(bufH, init, bufA, K8T, pw0,pb0,pw1,pb1,pwf,pbf, DTF);
    for (int s = 0; s < 3; ++s) {
        rhs_kernel<<<grid, block, 0, stream>>>(bufA, bufA, bufH, K8T, pw0,pb0,pw1,pb1,pwf,pbf, DTH);
        rhs_kernel<<<grid, block, 0, stream>>>(bufH, bufA, bufA, K8T, pw0,pb0,pw1,pb1,pwf,pbf, DTF);
    }
    rhs_kernel<<<grid, block, 0, stream>>>(bufA, bufA, bufH, K8T, pw0,pb0,pw1,pb1,pwf,pbf, DTH);
    rhs_kernel<<<grid, block, 0, stream>>>(bufH, bufA, out,  K8T, pw0,pb0,pw1,pb1,pwf,pbf, DTF);
}